// Round 1
// baseline (138.267 us; speedup 1.0000x reference)
//
#include <hip/hip_runtime.h>

typedef __attribute__((ext_vector_type(8))) short bf16x8;
typedef __attribute__((ext_vector_type(4))) float f32x4;

#define D_MODEL 512
#define SEQ 2048
#define NB 2
#define NHEAD 8
#define HDIM 64
#define WIN 128

__device__ inline unsigned short f2bf(float f) {
    unsigned u = __float_as_uint(f);
    unsigned r = (u + 0x7fffu + ((u >> 16) & 1u)) >> 16;   // RNE
    return (unsigned short)r;
}
__device__ inline float bflo(unsigned u) { return __uint_as_float(u << 16); }
__device__ inline float bfhi(unsigned u) { return __uint_as_float(u & 0xffff0000u); }

__device__ inline void async_load16(const void* g, void* l) {
    __builtin_amdgcn_global_load_lds((const __attribute__((address_space(1))) void*)g,
                                     (__attribute__((address_space(3))) void*)l, 16, 0, 0);
}

// ---------------- conversion kernels ----------------
__global__ __launch_bounds__(256) void conv_x(const float* __restrict__ x,
                                              unsigned short* __restrict__ xc) {
    int i = blockIdx.x * 256 + threadIdx.x;          // one float4 per thread
    float4 v = ((const float4*)x)[i];
    ushort4 o;
    o.x = f2bf(v.x); o.y = f2bf(v.y); o.z = f2bf(v.z); o.w = f2bf(v.w);
    ((ushort4*)xc)[i] = o;
}

// Wt[mat][n][k] = bf16(W[mat][k][n]) — LDS-tiled transpose
__global__ __launch_bounds__(256) void conv_wt(const float* __restrict__ Wq,
                                               const float* __restrict__ Wk,
                                               const float* __restrict__ Wv,
                                               const float* __restrict__ Wo,
                                               unsigned short* __restrict__ Wt) {
    __shared__ float tile[32 * 33];
    const int mat = blockIdx.z;
    const float* W = mat == 0 ? Wq : mat == 1 ? Wk : mat == 2 ? Wv : Wo;
    const int ti = blockIdx.x, tj = blockIdx.y;      // k-tile, n-tile
    const int t = threadIdx.x;
    {
        int c = t & 31, r4 = (t >> 5) * 4;
        #pragma unroll
        for (int e = 0; e < 4; e++)
            tile[(r4 + e) * 33 + c] = W[(size_t)(ti * 32 + r4 + e) * 512 + tj * 32 + c];
    }
    __syncthreads();
    {
        int rr = t & 31, c4 = (t >> 5) * 4;
        #pragma unroll
        for (int e = 0; e < 4; e++)
            Wt[(size_t)mat * 262144 + (size_t)(tj * 32 + c4 + e) * 512 + ti * 32 + rr] =
                f2bf(tile[rr * 33 + c4 + e]);
    }
}

// ---------------- bf16 MFMA GEMM: C[M][Nstride] = A[M][512] @ Bt[N][512]^T --------
__device__ inline void storeC(float* C, size_t i, float v) { C[i] = v; }
__device__ inline void storeC(unsigned short* C, size_t i, float v) { C[i] = f2bf(v); }

template <typename OUT>
__global__ __launch_bounds__(256) void gemm_bt(const unsigned short* __restrict__ A,
                                               const unsigned short* __restrict__ Bt,
                                               OUT* __restrict__ C, int Nstride) {
    __shared__ unsigned short As[128 * 32];
    __shared__ unsigned short Bs[128 * 32];
    const int t = threadIdx.x;
    const int w = t >> 6, l = t & 63;
    const int mBase = blockIdx.x * 128;
    const int nBase = blockIdx.y * 128;
    // staging: thread t covers row t>>2, k-chunk (t&3)*8 (16B) in each 64-row half
    const int r0 = t >> 2, koff = (t & 3) * 8;
    const unsigned short* a0 = A + (size_t)(mBase + r0) * 512 + koff;
    const unsigned short* a1 = A + (size_t)(mBase + 64 + r0) * 512 + koff;
    const unsigned short* b0 = Bt + (size_t)(nBase + r0) * 512 + koff;
    const unsigned short* b1 = Bt + (size_t)(nBase + 64 + r0) * 512 + koff;
    unsigned short* asd0 = &As[t * 8];
    unsigned short* asd1 = &As[2048 + t * 8];
    unsigned short* bsd0 = &Bs[t * 8];
    unsigned short* bsd1 = &Bs[2048 + t * 8];

    const int lane_m = l & 15;
    const int kg = (l >> 4) * 8;
    const int wr = (w >> 1) * 64, wc = (w & 1) * 64;

    f32x4 acc[4][4];
    #pragma unroll
    for (int i = 0; i < 4; i++)
        #pragma unroll
        for (int j = 0; j < 4; j++) acc[i][j] = (f32x4){0.f, 0.f, 0.f, 0.f};

    for (int k0 = 0; k0 < 512; k0 += 32) {
        async_load16(a0 + k0, asd0);
        async_load16(a1 + k0, asd1);
        async_load16(b0 + k0, bsd0);
        async_load16(b1 + k0, bsd1);
        __syncthreads();   // drains vmcnt → LDS tiles complete
        bf16x8 af[4], bfr[4];
        #pragma unroll
        for (int i = 0; i < 4; i++)
            af[i] = *(const bf16x8*)&As[(wr + i * 16 + lane_m) * 32 + kg];
        #pragma unroll
        for (int j = 0; j < 4; j++)
            bfr[j] = *(const bf16x8*)&Bs[(wc + j * 16 + lane_m) * 32 + kg];
        #pragma unroll
        for (int i = 0; i < 4; i++)
            #pragma unroll
            for (int j = 0; j < 4; j++)
                acc[i][j] = __builtin_amdgcn_mfma_f32_16x16x32_bf16(af[i], bfr[j], acc[i][j], 0, 0, 0);
        __syncthreads();
    }
    // epilogue: C/D map col=lane&15, row=(lane>>4)*4+reg   [m89-verified]
    const int rRow = (l >> 4) * 4;
    const int cCol = l & 15;
    #pragma unroll
    for (int i = 0; i < 4; i++)
        #pragma unroll
        for (int j = 0; j < 4; j++)
            #pragma unroll
            for (int r = 0; r < 4; r++) {
                size_t row = (size_t)(mBase + wr + i * 16 + rRow + r);
                size_t col = (size_t)(nBase + wc + j * 16 + cCol);
                storeC(C, row * (size_t)Nstride + col, acc[i][j][r]);
            }
}

// ---------------- sliding-window attention (fp32 core, bf16 K/V/Q in LDS) --------
// QKV: [B*S][1536] bf16, cols 0..511 Q | 512..1023 K | 1024..1535 V
// AO : [B*S][512] bf16 (merged heads)
__global__ __launch_bounds__(256) void attn_kernel(const unsigned short* __restrict__ QKV,
                                                   unsigned short* __restrict__ AO) {
    __shared__ unsigned short Ks[160 * 64];   // rows r=0..158 ↔ key g = s0-127+r, XOR-swizzled chunks
    __shared__ unsigned short Vs[160 * 64];
    __shared__ unsigned short Qs[32 * 72];    // padded stride
    __shared__ float P[32 * 130];
    __shared__ float Linv[32];

    const int t = threadIdx.x;
    const int s0 = blockIdx.x * 32;
    const int h = blockIdx.y;
    const int b = blockIdx.z;
    const unsigned short* base = QKV + (size_t)b * SEQ * 1536;
    const int hq = h * 64, hk = 512 + h * 64, hv = 1024 + h * 64;

    // stage K/V window rows (clamped; invalid rows masked later, clamp keeps data finite)
    for (int idx = t; idx < 159 * 8; idx += 256) {
        int r = idx >> 3, c8 = idx & 7;
        int g = s0 - 127 + r;
        g = g < 0 ? 0 : g;
        uint4 kv = *(const uint4*)(base + (size_t)g * 1536 + hk + c8 * 8);
        uint4 vv = *(const uint4*)(base + (size_t)g * 1536 + hv + c8 * 8);
        int sw = ((c8 ^ (r & 7)) * 8);
        *(uint4*)&Ks[r * 64 + sw] = kv;
        *(uint4*)&Vs[r * 64 + sw] = vv;
    }
    {   // stage Q: 32 rows × 8 chunks = 256 threads exactly
        int r = t >> 3, c8 = t & 7;
        *(uint4*)&Qs[r * 72 + c8 * 8] = *(const uint4*)(base + (size_t)(s0 + r) * 1536 + hq + c8 * 8);
    }
    __syncthreads();

    // scores: thread → (q = t&31, j-block = (t>>5)*16)
    {
        const int q = t & 31, jb = (t >> 5) * 16;
        float acc[16];
        #pragma unroll
        for (int i = 0; i < 16; i++) acc[i] = 0.f;
        #pragma unroll
        for (int dc = 0; dc < 8; dc++) {
            uint4 qv = *(const uint4*)&Qs[q * 72 + dc * 8];
            float qf[8];
            qf[0] = bflo(qv.x); qf[1] = bfhi(qv.x);
            qf[2] = bflo(qv.y); qf[3] = bfhi(qv.y);
            qf[4] = bflo(qv.z); qf[5] = bfhi(qv.z);
            qf[6] = bflo(qv.w); qf[7] = bfhi(qv.w);
            #pragma unroll
            for (int i = 0; i < 16; i++) {
                int r = q + jb + i;
                uint4 kv = *(const uint4*)&Ks[r * 64 + ((dc ^ (r & 7)) * 8)];
                acc[i] = fmaf(qf[0], bflo(kv.x), acc[i]);
                acc[i] = fmaf(qf[1], bfhi(kv.x), acc[i]);
                acc[i] = fmaf(qf[2], bflo(kv.y), acc[i]);
                acc[i] = fmaf(qf[3], bfhi(kv.y), acc[i]);
                acc[i] = fmaf(qf[4], bflo(kv.z), acc[i]);
                acc[i] = fmaf(qf[5], bfhi(kv.z), acc[i]);
                acc[i] = fmaf(qf[6], bflo(kv.w), acc[i]);
                acc[i] = fmaf(qf[7], bfhi(kv.w), acc[i]);
            }
        }
        #pragma unroll
        for (int i = 0; i < 16; i++) {
            int j = jb + i;
            int g = s0 + q - 127 + j;
            P[q * 130 + j] = (g >= 0) ? acc[i] * 0.125f : -1e30f;
        }
    }
    __syncthreads();

    // softmax: 8 threads per query (contiguous lanes) via shfl_xor 1,2,4
    {
        const int q = t >> 3, c = t & 7;
        float v[16];
        float m = -1e30f;
        #pragma unroll
        for (int i = 0; i < 16; i++) { v[i] = P[q * 130 + c * 16 + i]; m = fmaxf(m, v[i]); }
        m = fmaxf(m, __shfl_xor(m, 1));
        m = fmaxf(m, __shfl_xor(m, 2));
        m = fmaxf(m, __shfl_xor(m, 4));
        float s = 0.f;
        #pragma unroll
        for (int i = 0; i < 16; i++) { v[i] = __expf(v[i] - m); s += v[i]; }
        s += __shfl_xor(s, 1);
        s += __shfl_xor(s, 2);
        s += __shfl_xor(s, 4);
        #pragma unroll
        for (int i = 0; i < 16; i++) P[q * 130 + c * 16 + i] = v[i];
        if (c == 0) Linv[q] = 1.f / s;
    }
    __syncthreads();

    // PV: thread → (q = t>>3, d-chunk = t&7)
    {
        const int q = t >> 3, dc = t & 7;
        float o[8];
        #pragma unroll
        for (int e = 0; e < 8; e++) o[e] = 0.f;
        #pragma unroll 4
        for (int j = 0; j < 128; j++) {
            float p = P[q * 130 + j];
            int r = q + j;
            uint4 vv = *(const uint4*)&Vs[r * 64 + ((dc ^ (r & 7)) * 8)];
            o[0] = fmaf(p, bflo(vv.x), o[0]);
            o[1] = fmaf(p, bfhi(vv.x), o[1]);
            o[2] = fmaf(p, bflo(vv.y), o[2]);
            o[3] = fmaf(p, bfhi(vv.y), o[3]);
            o[4] = fmaf(p, bflo(vv.z), o[4]);
            o[5] = fmaf(p, bfhi(vv.z), o[5]);
            o[6] = fmaf(p, bflo(vv.w), o[6]);
            o[7] = fmaf(p, bfhi(vv.w), o[7]);
        }
        float li = Linv[q];
        unsigned short tmp[8];
        #pragma unroll
        for (int e = 0; e < 8; e++) tmp[e] = f2bf(o[e] * li);
        uint4 ov;
        ov.x = (unsigned)tmp[0] | ((unsigned)tmp[1] << 16);
        ov.y = (unsigned)tmp[2] | ((unsigned)tmp[3] << 16);
        ov.z = (unsigned)tmp[4] | ((unsigned)tmp[5] << 16);
        ov.w = (unsigned)tmp[6] | ((unsigned)tmp[7] << 16);
        *(uint4*)(AO + ((size_t)(b * SEQ + s0 + q)) * 512 + h * 64 + dc * 8) = ov;
    }
}

extern "C" void kernel_launch(void* const* d_in, const int* in_sizes, int n_in,
                              void* d_out, int out_size, void* d_ws, size_t ws_size,
                              hipStream_t stream) {
    const float* x  = (const float*)d_in[0];
    const float* Wq = (const float*)d_in[1];
    const float* Wk = (const float*)d_in[2];
    const float* Wv = (const float*)d_in[3];
    const float* Wo = (const float*)d_in[4];
    float* out = (float*)d_out;

    char* ws = (char*)d_ws;
    unsigned short* xc  = (unsigned short*)ws;                          // 4096*512  bf16 (4 MiB)
    unsigned short* Wt  = (unsigned short*)(ws + 4u * 1024 * 1024);     // 4*512*512 bf16 (2 MiB), order q,k,v,o
    unsigned short* QKV = (unsigned short*)(ws + 6u * 1024 * 1024);     // 4096*1536 bf16 (12 MiB)
    unsigned short* AO  = (unsigned short*)(ws + 18u * 1024 * 1024);    // 4096*512  bf16 (4 MiB)

    conv_x<<<2048, 256, 0, stream>>>(x, xc);
    conv_wt<<<dim3(16, 16, 4), 256, 0, stream>>>(Wq, Wk, Wv, Wo, Wt);
    // fused QKV projection: Bt = [Wq^T; Wk^T; Wv^T] (N = 1536)
    gemm_bt<unsigned short><<<dim3(32, 12), 256, 0, stream>>>(xc, Wt, QKV, 1536);
    attn_kernel<<<dim3(64, 8, 2), 256, 0, stream>>>(QKV, AO);
    // output projection: N = 512, fp32 out
    gemm_bt<float><<<dim3(32, 4), 256, 0, stream>>>(AO, Wt + 3 * 262144, out, 512);
}

// Round 2
// 124.411 us; speedup vs baseline: 1.1114x; 1.1114x over previous
//
#include <hip/hip_runtime.h>

typedef __attribute__((ext_vector_type(8))) short bf16x8;
typedef __attribute__((ext_vector_type(4))) float f32x4;

#define D_MODEL 512
#define SEQ 2048
#define NB 2
#define NHEAD 8
#define HDIM 64
#define WIN 128

__device__ inline unsigned short f2bf(float f) {
    unsigned u = __float_as_uint(f);
    unsigned r = (u + 0x7fffu + ((u >> 16) & 1u)) >> 16;   // RNE
    return (unsigned short)r;
}

__device__ inline void async_load16(const void* g, void* l) {
    __builtin_amdgcn_global_load_lds((const __attribute__((address_space(1))) void*)g,
                                     (__attribute__((address_space(3))) void*)l, 16, 0, 0);
}

// ---------------- conversion kernels ----------------
__global__ __launch_bounds__(256) void conv_x(const float* __restrict__ x,
                                              unsigned short* __restrict__ xc) {
    int i = blockIdx.x * 256 + threadIdx.x;
    float4 v = ((const float4*)x)[i];
    ushort4 o;
    o.x = f2bf(v.x); o.y = f2bf(v.y); o.z = f2bf(v.z); o.w = f2bf(v.w);
    ((ushort4*)xc)[i] = o;
}

__global__ __launch_bounds__(256) void zero_out(float4* __restrict__ p) {
    p[blockIdx.x * 256 + threadIdx.x] = (float4){0.f, 0.f, 0.f, 0.f};
}

// Wt[mat][n][k] = bf16(W[mat][k][n])
__global__ __launch_bounds__(256) void conv_wt(const float* __restrict__ Wq,
                                               const float* __restrict__ Wk,
                                               const float* __restrict__ Wv,
                                               const float* __restrict__ Wo,
                                               unsigned short* __restrict__ Wt) {
    __shared__ float tile[32 * 33];
    const int mat = blockIdx.z;
    const float* W = mat == 0 ? Wq : mat == 1 ? Wk : mat == 2 ? Wv : Wo;
    const int ti = blockIdx.x, tj = blockIdx.y;
    const int t = threadIdx.x;
    {
        int c = t & 31, r4 = (t >> 5) * 4;
        #pragma unroll
        for (int e = 0; e < 4; e++)
            tile[(r4 + e) * 33 + c] = W[(size_t)(ti * 32 + r4 + e) * 512 + tj * 32 + c];
    }
    __syncthreads();
    {
        int rr = t & 31, c4 = (t >> 5) * 4;
        #pragma unroll
        for (int e = 0; e < 4; e++)
            Wt[(size_t)mat * 262144 + (size_t)(tj * 32 + c4 + e) * 512 + ti * 32 + rr] =
                f2bf(tile[rr * 33 + c4 + e]);
    }
}

// ---------------- bf16 MFMA GEMM: C[M][Nstride] = A[M][512] @ Bt[N][512]^T --------
__device__ inline void storeC(float* C, size_t i, float v) { C[i] = v; }
__device__ inline void storeC(unsigned short* C, size_t i, float v) { C[i] = f2bf(v); }

template <typename OUT, bool ATOMIC>
__global__ __launch_bounds__(256) void gemm_bt(const unsigned short* __restrict__ A,
                                               const unsigned short* __restrict__ Bt,
                                               OUT* __restrict__ C, int Nstride,
                                               int kPerSplit) {
    __shared__ unsigned short As[128 * 32];
    __shared__ unsigned short Bs[128 * 32];
    const int t = threadIdx.x;
    const int w = t >> 6, l = t & 63;
    const int mBase = blockIdx.x * 128;
    const int nBase = blockIdx.y * 128;
    const int kBase = blockIdx.z * kPerSplit;
    const int r0 = t >> 2, koff = (t & 3) * 8;
    const unsigned short* a0 = A + (size_t)(mBase + r0) * 512 + koff;
    const unsigned short* a1 = A + (size_t)(mBase + 64 + r0) * 512 + koff;
    const unsigned short* b0 = Bt + (size_t)(nBase + r0) * 512 + koff;
    const unsigned short* b1 = Bt + (size_t)(nBase + 64 + r0) * 512 + koff;
    unsigned short* asd0 = &As[t * 8];
    unsigned short* asd1 = &As[2048 + t * 8];
    unsigned short* bsd0 = &Bs[t * 8];
    unsigned short* bsd1 = &Bs[2048 + t * 8];

    const int lane_m = l & 15;
    const int kg = (l >> 4) * 8;
    const int wr = (w >> 1) * 64, wc = (w & 1) * 64;

    f32x4 acc[4][4];
    #pragma unroll
    for (int i = 0; i < 4; i++)
        #pragma unroll
        for (int j = 0; j < 4; j++) acc[i][j] = (f32x4){0.f, 0.f, 0.f, 0.f};

    for (int k0 = kBase; k0 < kBase + kPerSplit; k0 += 32) {
        async_load16(a0 + k0, asd0);
        async_load16(a1 + k0, asd1);
        async_load16(b0 + k0, bsd0);
        async_load16(b1 + k0, bsd1);
        __syncthreads();
        bf16x8 af[4], bfr[4];
        #pragma unroll
        for (int i = 0; i < 4; i++)
            af[i] = *(const bf16x8*)&As[(wr + i * 16 + lane_m) * 32 + kg];
        #pragma unroll
        for (int j = 0; j < 4; j++)
            bfr[j] = *(const bf16x8*)&Bs[(wc + j * 16 + lane_m) * 32 + kg];
        #pragma unroll
        for (int i = 0; i < 4; i++)
            #pragma unroll
            for (int j = 0; j < 4; j++)
                acc[i][j] = __builtin_amdgcn_mfma_f32_16x16x32_bf16(af[i], bfr[j], acc[i][j], 0, 0, 0);
        __syncthreads();
    }
    const int rRow = (l >> 4) * 4;
    const int cCol = l & 15;
    #pragma unroll
    for (int i = 0; i < 4; i++)
        #pragma unroll
        for (int j = 0; j < 4; j++)
            #pragma unroll
            for (int r = 0; r < 4; r++) {
                size_t row = (size_t)(mBase + wr + i * 16 + rRow + r);
                size_t col = (size_t)(nBase + wc + j * 16 + cCol);
                if (ATOMIC)
                    unsafeAtomicAdd((float*)&C[row * (size_t)Nstride + col], acc[i][j][r]);
                else
                    storeC(C, row * (size_t)Nstride + col, acc[i][j][r]);
            }
}

// ---------------- V transpose: QKV V-block -> Vt[(b*8+h)*64+d][s] ----------------
__global__ __launch_bounds__(256) void transpose_v(const unsigned short* __restrict__ QKV,
                                                   unsigned short* __restrict__ Vtg) {
    __shared__ unsigned short tile[64 * 72];
    const int t = threadIdx.x;
    const int s0 = blockIdx.x * 64, h = blockIdx.y, b = blockIdx.z;
    const unsigned short* base = QKV + (size_t)b * SEQ * 1536 + 1024 + h * 64;
    for (int i = t; i < 64 * 8; i += 256) {
        int r = i >> 3, c8 = i & 7;
        *(uint4*)&tile[r * 72 + c8 * 8] = *(const uint4*)(base + (size_t)(s0 + r) * 1536 + c8 * 8);
    }
    __syncthreads();
    for (int i = t; i < 64 * 8; i += 256) {
        int d = i >> 3, c8 = i & 7;
        unsigned short tmp[8];
        #pragma unroll
        for (int e = 0; e < 8; e++) tmp[e] = tile[(c8 * 8 + e) * 72 + d];
        uint4 ov;
        ov.x = (unsigned)tmp[0] | ((unsigned)tmp[1] << 16);
        ov.y = (unsigned)tmp[2] | ((unsigned)tmp[3] << 16);
        ov.z = (unsigned)tmp[4] | ((unsigned)tmp[5] << 16);
        ov.w = (unsigned)tmp[6] | ((unsigned)tmp[7] << 16);
        *(uint4*)(Vtg + ((size_t)(b * 8 + h) * 64 + d) * SEQ + s0 + c8 * 8) = ov;
    }
}

// ---------------- MFMA sliding-window attention ----------------
// Block: 64 queries x 1 head x 1 batch; 4 waves, wave w -> queries [w*16, w*16+16)
// Keys j=0..191 <-> g = s0-127+j. Valid: j in [max(qi,127-s0), qi+127].
__global__ __launch_bounds__(256) void attn_mfma(const unsigned short* __restrict__ QKV,
                                                 const unsigned short* __restrict__ Vtg,
                                                 unsigned short* __restrict__ AO) {
    __shared__ unsigned short Ks[192 * 72];   // [key j][feat], stride 72
    __shared__ unsigned short Qs[64 * 72];    // [q][feat]
    __shared__ unsigned short Vs[64 * 200];   // [d][key j], stride 200
    __shared__ unsigned short Pb[4][16 * 40]; // per-wave P bounce, stride 40

    const int t = threadIdx.x;
    const int w = t >> 6, l = t & 63;
    const int s0 = blockIdx.x * 64;
    const int h = blockIdx.y, b = blockIdx.z;
    const unsigned short* base = QKV + (size_t)b * SEQ * 1536;

    // stage K (192 rows, clamped g; invalid j masked later)
    for (int i = t; i < 192 * 8; i += 256) {
        int j = i >> 3, c8 = i & 7;
        int g = s0 - 127 + j;
        g = g < 0 ? 0 : (g > SEQ - 1 ? SEQ - 1 : g);
        *(uint4*)&Ks[j * 72 + c8 * 8] =
            *(const uint4*)(base + (size_t)g * 1536 + 512 + h * 64 + c8 * 8);
    }
    // stage Q
    for (int i = t; i < 64 * 8; i += 256) {
        int r = i >> 3, c8 = i & 7;
        *(uint4*)&Qs[r * 72 + c8 * 8] =
            *(const uint4*)(base + (size_t)(s0 + r) * 1536 + h * 64 + c8 * 8);
    }
    // stage Vt rows (reads may touch the +-pad of Vtg; those keys are masked)
    const unsigned short* vrow0 = Vtg + ((size_t)(b * 8 + h) * 64) * SEQ + (s0 - 127);
    for (int i = t; i < 64 * 24; i += 256) {
        int d = i / 24, c = i % 24;
        *(uint4*)&Vs[d * 200 + c * 8] = *(const uint4*)(vrow0 + (size_t)d * SEQ + c * 8);
    }
    __syncthreads();

    const int lm = l & 15, lk = (l >> 4) * 8;

    // ---- scores: S[16 q][192 j] via MFMA ----
    f32x4 sc[12];
    #pragma unroll
    for (int kb = 0; kb < 12; kb++) sc[kb] = (f32x4){0.f, 0.f, 0.f, 0.f};
    bf16x8 aq[2];
    #pragma unroll
    for (int ks = 0; ks < 2; ks++)
        aq[ks] = *(const bf16x8*)&Qs[(w * 16 + lm) * 72 + ks * 32 + lk];
    #pragma unroll
    for (int kb = 0; kb < 12; kb++) {
        #pragma unroll
        for (int ks = 0; ks < 2; ks++) {
            bf16x8 bk = *(const bf16x8*)&Ks[(kb * 16 + lm) * 72 + ks * 32 + lk];
            sc[kb] = __builtin_amdgcn_mfma_f32_16x16x32_bf16(aq[ks], bk, sc[kb], 0, 0, 0);
        }
    }

    // ---- mask + scale + in-register softmax ----
    // C layout: col j = kb*16 + lm, row qi = w*16 + (l>>4)*4 + r
    const int qr0 = (l >> 4) * 4;          // block-local row base within wave tile
    const int jlo_g = 127 - s0;            // g>=0 constraint
    float mrow[4] = {-1e30f, -1e30f, -1e30f, -1e30f};
    #pragma unroll
    for (int kb = 0; kb < 12; kb++) {
        int j = kb * 16 + lm;
        #pragma unroll
        for (int r = 0; r < 4; r++) {
            int qi = w * 16 + qr0 + r;
            bool valid = (j >= qi) & (j <= qi + 127) & (j >= jlo_g);
            float v = valid ? sc[kb][r] * 0.125f : -1e30f;
            sc[kb][r] = v;
            mrow[r] = fmaxf(mrow[r], v);
        }
    }
    #pragma unroll
    for (int r = 0; r < 4; r++) {
        mrow[r] = fmaxf(mrow[r], __shfl_xor(mrow[r], 1));
        mrow[r] = fmaxf(mrow[r], __shfl_xor(mrow[r], 2));
        mrow[r] = fmaxf(mrow[r], __shfl_xor(mrow[r], 4));
        mrow[r] = fmaxf(mrow[r], __shfl_xor(mrow[r], 8));
    }
    float srow[4] = {0.f, 0.f, 0.f, 0.f};
    #pragma unroll
    for (int kb = 0; kb < 12; kb++)
        #pragma unroll
        for (int r = 0; r < 4; r++) {
            float p = __expf(sc[kb][r] - mrow[r]);
            sc[kb][r] = p;
            srow[r] += p;
        }
    #pragma unroll
    for (int r = 0; r < 4; r++) {
        srow[r] += __shfl_xor(srow[r], 1);
        srow[r] += __shfl_xor(srow[r], 2);
        srow[r] += __shfl_xor(srow[r], 4);
        srow[r] += __shfl_xor(srow[r], 8);
        srow[r] = 1.f / srow[r];
    }

    // ---- PV: O[16 q][64 d], P chunk -> LDS bounce -> A-frag ----
    f32x4 ov[4];
    #pragma unroll
    for (int nb = 0; nb < 4; nb++) ov[nb] = (f32x4){0.f, 0.f, 0.f, 0.f};
    unsigned short* pb = &Pb[w][0];
    #pragma unroll
    for (int c = 0; c < 6; c++) {
        #pragma unroll
        for (int kk = 0; kk < 2; kk++)
            #pragma unroll
            for (int r = 0; r < 4; r++)
                pb[(qr0 + r) * 40 + kk * 16 + lm] = f2bf(sc[2 * c + kk][r]);
        // same-wave write->read: compiler orders via lgkmcnt (same LDS object)
        bf16x8 ap = *(const bf16x8*)&pb[lm * 40 + lk];
        #pragma unroll
        for (int nb = 0; nb < 4; nb++) {
            bf16x8 bv = *(const bf16x8*)&Vs[(nb * 16 + lm) * 200 + c * 32 + lk];
            ov[nb] = __builtin_amdgcn_mfma_f32_16x16x32_bf16(ap, bv, ov[nb], 0, 0, 0);
        }
    }

    // ---- epilogue: normalize rows, store bf16 ----
    #pragma unroll
    for (int nb = 0; nb < 4; nb++)
        #pragma unroll
        for (int r = 0; r < 4; r++) {
            size_t row = (size_t)(b * SEQ + s0 + w * 16 + qr0 + r);
            AO[row * 512 + h * 64 + nb * 16 + lm] = f2bf(ov[nb][r] * srow[r]);
        }
}

extern "C" void kernel_launch(void* const* d_in, const int* in_sizes, int n_in,
                              void* d_out, int out_size, void* d_ws, size_t ws_size,
                              hipStream_t stream) {
    const float* x  = (const float*)d_in[0];
    const float* Wq = (const float*)d_in[1];
    const float* Wk = (const float*)d_in[2];
    const float* Wv = (const float*)d_in[3];
    const float* Wo = (const float*)d_in[4];
    float* out = (float*)d_out;

    char* ws = (char*)d_ws;
    unsigned short* xc  = (unsigned short*)ws;                          // 4 MiB
    unsigned short* Wt  = (unsigned short*)(ws + 4u * 1024 * 1024);     // 2 MiB
    unsigned short* QKV = (unsigned short*)(ws + 6u * 1024 * 1024);     // 12 MiB
    unsigned short* AO  = (unsigned short*)(ws + 18u * 1024 * 1024);    // 4 MiB
    // Vt with 2 KiB front/back pad (attention reads s0-127 .. s0+64)
    unsigned short* Vtg = (unsigned short*)(ws + 22u * 1024 * 1024 + 2048);  // 4 MiB + pads

    conv_x<<<2048, 256, 0, stream>>>(x, xc);
    conv_wt<<<dim3(16, 16, 4), 256, 0, stream>>>(Wq, Wk, Wv, Wo, Wt);
    zero_out<<<2048, 256, 0, stream>>>((float4*)out);
    // fused QKV projection (N = 1536, full K)
    gemm_bt<unsigned short, false><<<dim3(32, 12, 1), 256, 0, stream>>>(xc, Wt, QKV, 1536, 512);
    transpose_v<<<dim3(32, 8, 2), 256, 0, stream>>>(QKV, Vtg);
    attn_mfma<<<dim3(32, 8, 2), 256, 0, stream>>>(QKV, Vtg, AO);
    // output projection: split-K=2, atomic fp32 accumulate
    gemm_bt<float, true><<<dim3(32, 4, 2), 256, 0, stream>>>(AO, Wt + 3 * 262144, out, 512, 256);
}

// Round 3
// 104.358 us; speedup vs baseline: 1.3249x; 1.1922x over previous
//
#include <hip/hip_runtime.h>

typedef __attribute__((ext_vector_type(8))) short bf16x8;
typedef __attribute__((ext_vector_type(4))) float f32x4;

#define D_MODEL 512
#define SEQ 2048
#define NHEAD 8
#define WIN 128

__device__ inline unsigned short f2bf(float f) {
    unsigned u = __float_as_uint(f);
    unsigned r = (u + 0x7fffu + ((u >> 16) & 1u)) >> 16;   // RNE
    return (unsigned short)r;
}

__device__ inline void async_load16(const void* g, void* l) {
    __builtin_amdgcn_global_load_lds((const __attribute__((address_space(1))) void*)g,
                                     (__attribute__((address_space(3))) void*)l, 16, 0, 0);
}

// ---------------- fused prep: bf16(x) + transposed bf16 weights ----------------
// blocks [0,2048): conv x (float4/thread). blocks [2048,3072): weight transpose.
__global__ __launch_bounds__(256) void prep(const float* __restrict__ x,
                                            const float* __restrict__ Wq,
                                            const float* __restrict__ Wk,
                                            const float* __restrict__ Wv,
                                            const float* __restrict__ Wo,
                                            unsigned short* __restrict__ xc,
                                            unsigned short* __restrict__ Wt) {
    __shared__ float tile[32 * 33];
    const int t = threadIdx.x;
    if (blockIdx.x < 2048) {
        int i = blockIdx.x * 256 + t;
        float4 v = ((const float4*)x)[i];
        ushort4 o;
        o.x = f2bf(v.x); o.y = f2bf(v.y); o.z = f2bf(v.z); o.w = f2bf(v.w);
        ((ushort4*)xc)[i] = o;
        return;
    }
    int idx = blockIdx.x - 2048;             // 1024 blocks: 4 mats x 16 x 16 tiles
    const int mat = idx >> 8;
    const int rem = idx & 255;
    const int ti = rem & 15, tj = rem >> 4;  // k-tile, n-tile
    const float* W = mat == 0 ? Wq : mat == 1 ? Wk : mat == 2 ? Wv : Wo;
    {
        int c = t & 31, r4 = (t >> 5) * 4;
        #pragma unroll
        for (int e = 0; e < 4; e++)
            tile[(r4 + e) * 33 + c] = W[(size_t)(ti * 32 + r4 + e) * 512 + tj * 32 + c];
    }
    __syncthreads();
    {
        int rr = t & 31, c4 = (t >> 5) * 4;
        #pragma unroll
        for (int e = 0; e < 4; e++)
            Wt[(size_t)mat * 262144 + (size_t)(tj * 32 + c4 + e) * 512 + ti * 32 + rr] =
                f2bf(tile[rr * 33 + c4 + e]);
    }
}

// ---------------- 64-row-tile bf16 MFMA GEMM: C[M][Nstride] = A @ Bt^T ----------
// Tile 64 x (NT*16). 4 waves; wave w owns rows [w*16, w*16+16). K = 512 fixed.
__device__ inline void storeC(float* C, size_t i, float v) { C[i] = v; }
__device__ inline void storeC(unsigned short* C, size_t i, float v) { C[i] = f2bf(v); }

template <typename OUT, int NT>
__global__ __launch_bounds__(256) void gemm64(const unsigned short* __restrict__ A,
                                              const unsigned short* __restrict__ Bt,
                                              OUT* __restrict__ C, int Nstride) {
    __shared__ unsigned short As[64 * 32];
    __shared__ unsigned short Bs[NT * 16 * 32];
    const int t = threadIdx.x;
    const int w = t >> 6, l = t & 63;
    const int mBase = blockIdx.x * 64;
    const int nBase = blockIdx.y * (NT * 16);
    const int r0 = t >> 2, koff = (t & 3) * 8;
    const unsigned short* a0 = A + (size_t)(mBase + r0) * 512 + koff;
    const unsigned short* b0 = Bt + (size_t)(nBase + r0) * 512 + koff;
    const unsigned short* b1 = Bt + (size_t)(nBase + 64 + r0) * 512 + koff;  // NT==8 only
    unsigned short* asd  = &As[t * 8];
    unsigned short* bsd0 = &Bs[t * 8];
    unsigned short* bsd1 = &Bs[2048 + t * 8];

    const int lm = l & 15;
    const int kg = (l >> 4) * 8;

    f32x4 acc[NT];
    #pragma unroll
    for (int j = 0; j < NT; j++) acc[j] = (f32x4){0.f, 0.f, 0.f, 0.f};

    for (int k0 = 0; k0 < 512; k0 += 32) {
        async_load16(a0 + k0, asd);
        async_load16(b0 + k0, bsd0);
        if (NT == 8) async_load16(b1 + k0, bsd1);
        __syncthreads();
        bf16x8 af = *(const bf16x8*)&As[(w * 16 + lm) * 32 + kg];
        #pragma unroll
        for (int j = 0; j < NT; j++) {
            bf16x8 bfr = *(const bf16x8*)&Bs[(j * 16 + lm) * 32 + kg];
            acc[j] = __builtin_amdgcn_mfma_f32_16x16x32_bf16(af, bfr, acc[j], 0, 0, 0);
        }
        __syncthreads();
    }
    // C/D map: col = lane&15, row = (lane>>4)*4 + reg  [m89-verified]
    const int rRow = (l >> 4) * 4;
    const int cCol = l & 15;
    #pragma unroll
    for (int j = 0; j < NT; j++)
        #pragma unroll
        for (int r = 0; r < 4; r++) {
            size_t row = (size_t)(mBase + w * 16 + rRow + r);
            size_t col = (size_t)(nBase + j * 16 + cCol);
            storeC(C, row * (size_t)Nstride + col, acc[j][r]);
        }
}

// ---------------- MFMA sliding-window attention (in-LDS V transpose) ------------
// Block: 64 queries x 1 head x 1 batch; wave w -> queries [w*16, w*16+16).
// Keys j=0..191 <-> g = s0-127+j. Valid: j in [max(qi,127-s0), qi+127].
__global__ __launch_bounds__(256) void attn_mfma(const unsigned short* __restrict__ QKV,
                                                 unsigned short* __restrict__ AO) {
    __shared__ unsigned short Ks[192 * 72];   // [key j][feat]
    __shared__ unsigned short Qs[64 * 72];    // [q][feat]
    __shared__ unsigned short Vs[64 * 200];   // [d][key j], 16B chunks XOR-swizzled
    __shared__ unsigned short Pb[4][16 * 40]; // per-wave P bounce

    const int t = threadIdx.x;
    const int w = t >> 6, l = t & 63;
    const int s0 = blockIdx.x * 64;
    const int h = blockIdx.y, b = blockIdx.z;
    const unsigned short* base = QKV + (size_t)b * SEQ * 1536;

    // stage K rows (clamped g; invalid j masked later)
    for (int i = t; i < 192 * 8; i += 256) {
        int j = i >> 3, c8 = i & 7;
        int g = s0 - 127 + j;
        g = g < 0 ? 0 : (g > SEQ - 1 ? SEQ - 1 : g);
        *(uint4*)&Ks[j * 72 + c8 * 8] =
            *(const uint4*)(base + (size_t)g * 1536 + 512 + h * 64 + c8 * 8);
    }
    // stage Q
    for (int i = t; i < 64 * 8; i += 256) {
        int r = i >> 3, c8 = i & 7;
        *(uint4*)&Qs[r * 72 + c8 * 8] =
            *(const uint4*)(base + (size_t)(s0 + r) * 1536 + h * 64 + c8 * 8);
    }
    // stage V transposed: global row j (coalesced 16B) -> Vs[d][j] scalar writes.
    // chunk swizzle (j>>3)^(d>>3) spreads the d-stride-200 bank aliasing to 2-way.
    for (int i = t; i < 192 * 8; i += 256) {
        int j = i >> 3, c8 = i & 7;
        int g = s0 - 127 + j;
        g = g < 0 ? 0 : (g > SEQ - 1 ? SEQ - 1 : g);
        uint4 vv = *(const uint4*)(base + (size_t)g * 1536 + 1024 + h * 64 + c8 * 8);
        unsigned short e16[8];
        *(uint4*)e16 = vv;
        int chunk = (j >> 3) ^ c8;           // (d>>3)&7 == c8 for d in [8*c8, 8*c8+8)
        int off = chunk * 8 + (j & 7);
        #pragma unroll
        for (int e = 0; e < 8; e++)
            Vs[(c8 * 8 + e) * 200 + off] = e16[e];
    }
    __syncthreads();

    const int lm = l & 15, lk = (l >> 4) * 8;

    // ---- scores: S[16 q][192 j] via MFMA ----
    f32x4 sc[12];
    #pragma unroll
    for (int kb = 0; kb < 12; kb++) sc[kb] = (f32x4){0.f, 0.f, 0.f, 0.f};
    bf16x8 aq[2];
    #pragma unroll
    for (int ks = 0; ks < 2; ks++)
        aq[ks] = *(const bf16x8*)&Qs[(w * 16 + lm) * 72 + ks * 32 + lk];
    #pragma unroll
    for (int kb = 0; kb < 12; kb++) {
        #pragma unroll
        for (int ks = 0; ks < 2; ks++) {
            bf16x8 bk = *(const bf16x8*)&Ks[(kb * 16 + lm) * 72 + ks * 32 + lk];
            sc[kb] = __builtin_amdgcn_mfma_f32_16x16x32_bf16(aq[ks], bk, sc[kb], 0, 0, 0);
        }
    }

    // ---- mask + scale + in-register softmax ----
    const int qr0 = (l >> 4) * 4;
    const int jlo_g = 127 - s0;
    float mrow[4] = {-1e30f, -1e30f, -1e30f, -1e30f};
    #pragma unroll
    for (int kb = 0; kb < 12; kb++) {
        int j = kb * 16 + lm;
        #pragma unroll
        for (int r = 0; r < 4; r++) {
            int qi = w * 16 + qr0 + r;
            bool valid = (j >= qi) & (j <= qi + 127) & (j >= jlo_g);
            float v = valid ? sc[kb][r] * 0.125f : -1e30f;
            sc[kb][r] = v;
            mrow[r] = fmaxf(mrow[r], v);
        }
    }
    #pragma unroll
    for (int r = 0; r < 4; r++) {
        mrow[r] = fmaxf(mrow[r], __shfl_xor(mrow[r], 1));
        mrow[r] = fmaxf(mrow[r], __shfl_xor(mrow[r], 2));
        mrow[r] = fmaxf(mrow[r], __shfl_xor(mrow[r], 4));
        mrow[r] = fmaxf(mrow[r], __shfl_xor(mrow[r], 8));
    }
    float srow[4] = {0.f, 0.f, 0.f, 0.f};
    #pragma unroll
    for (int kb = 0; kb < 12; kb++)
        #pragma unroll
        for (int r = 0; r < 4; r++) {
            float p = __expf(sc[kb][r] - mrow[r]);
            sc[kb][r] = p;
            srow[r] += p;
        }
    #pragma unroll
    for (int r = 0; r < 4; r++) {
        srow[r] += __shfl_xor(srow[r], 1);
        srow[r] += __shfl_xor(srow[r], 2);
        srow[r] += __shfl_xor(srow[r], 4);
        srow[r] += __shfl_xor(srow[r], 8);
        srow[r] = 1.f / srow[r];
    }

    // ---- PV: O[16 q][64 d]; P -> per-wave LDS bounce -> A-frag ----
    f32x4 ov[4];
    #pragma unroll
    for (int nb = 0; nb < 4; nb++) ov[nb] = (f32x4){0.f, 0.f, 0.f, 0.f};
    unsigned short* pb = &Pb[w][0];
    #pragma unroll
    for (int c = 0; c < 6; c++) {
        #pragma unroll
        for (int kk = 0; kk < 2; kk++)
            #pragma unroll
            for (int r = 0; r < 4; r++)
                pb[(qr0 + r) * 40 + kk * 16 + lm] = f2bf(sc[2 * c + kk][r]);
        bf16x8 ap = *(const bf16x8*)&pb[lm * 40 + lk];
        #pragma unroll
        for (int nb = 0; nb < 4; nb++) {
            int d = nb * 16 + lm;
            int cj = c * 4 + (l >> 4);                  // logical 16B chunk of j
            int off = ((cj ^ ((d >> 3) & 7)) * 8);
            bf16x8 bv = *(const bf16x8*)&Vs[d * 200 + off];
            ov[nb] = __builtin_amdgcn_mfma_f32_16x16x32_bf16(ap, bv, ov[nb], 0, 0, 0);
        }
    }

    // ---- epilogue ----
    #pragma unroll
    for (int nb = 0; nb < 4; nb++)
        #pragma unroll
        for (int r = 0; r < 4; r++) {
            size_t row = (size_t)(b * SEQ + s0 + w * 16 + qr0 + r);
            AO[row * 512 + h * 64 + nb * 16 + lm] = f2bf(ov[nb][r] * srow[r]);
        }
}

extern "C" void kernel_launch(void* const* d_in, const int* in_sizes, int n_in,
                              void* d_out, int out_size, void* d_ws, size_t ws_size,
                              hipStream_t stream) {
    const float* x  = (const float*)d_in[0];
    const float* Wq = (const float*)d_in[1];
    const float* Wk = (const float*)d_in[2];
    const float* Wv = (const float*)d_in[3];
    const float* Wo = (const float*)d_in[4];
    float* out = (float*)d_out;

    char* ws = (char*)d_ws;
    unsigned short* xc  = (unsigned short*)ws;                          // 4 MiB
    unsigned short* Wt  = (unsigned short*)(ws + 4u * 1024 * 1024);     // 2 MiB
    unsigned short* QKV = (unsigned short*)(ws + 6u * 1024 * 1024);     // 12 MiB
    unsigned short* AO  = (unsigned short*)(ws + 18u * 1024 * 1024);    // 4 MiB

    prep<<<3072, 256, 0, stream>>>(x, Wq, Wk, Wv, Wo, xc, Wt);
    // fused QKV projection: 64x128 tiles -> 768 blocks (3/CU)
    gemm64<unsigned short, 8><<<dim3(64, 12), 256, 0, stream>>>(xc, Wt, QKV, 1536);
    attn_mfma<<<dim3(32, 8, 2), 256, 0, stream>>>(QKV, AO);
    // output projection: 64x64 tiles -> 512 blocks (2/CU), no split-K
    gemm64<float, 4><<<dim3(64, 8), 256, 0, stream>>>(AO, Wt + 3 * 262144, out, 512);
}

// Round 4
// 99.647 us; speedup vs baseline: 1.3876x; 1.0473x over previous
//
#include <hip/hip_runtime.h>

typedef __attribute__((ext_vector_type(8))) short bf16x8;
typedef __attribute__((ext_vector_type(4))) float f32x4;

#define D_MODEL 512
#define SEQ 2048
#define NHEAD 8
#define WIN 128

__device__ inline unsigned short f2bf(float f) {
    unsigned u = __float_as_uint(f);
    unsigned r = (u + 0x7fffu + ((u >> 16) & 1u)) >> 16;   // RNE
    return (unsigned short)r;
}

__device__ inline void async_load16(const void* g, void* l) {
    __builtin_amdgcn_global_load_lds((const __attribute__((address_space(1))) void*)g,
                                     (__attribute__((address_space(3))) void*)l, 16, 0, 0);
}

// ---------------- fused prep: bf16(x) + transposed bf16 weights ----------------
__global__ __launch_bounds__(256) void prep(const float* __restrict__ x,
                                            const float* __restrict__ Wq,
                                            const float* __restrict__ Wk,
                                            const float* __restrict__ Wv,
                                            const float* __restrict__ Wo,
                                            unsigned short* __restrict__ xc,
                                            unsigned short* __restrict__ Wt) {
    __shared__ float tile[32 * 33];
    const int t = threadIdx.x;
    if (blockIdx.x < 2048) {
        int i = blockIdx.x * 256 + t;
        float4 v = ((const float4*)x)[i];
        ushort4 o;
        o.x = f2bf(v.x); o.y = f2bf(v.y); o.z = f2bf(v.z); o.w = f2bf(v.w);
        ((ushort4*)xc)[i] = o;
        return;
    }
    int idx = blockIdx.x - 2048;             // 1024 blocks: 4 mats x 16 x 16 tiles
    const int mat = idx >> 8;
    const int rem = idx & 255;
    const int ti = rem & 15, tj = rem >> 4;  // k-tile, n-tile
    const float* W = mat == 0 ? Wq : mat == 1 ? Wk : mat == 2 ? Wv : Wo;
    {
        int c = t & 31, r4 = (t >> 5) * 4;
        #pragma unroll
        for (int e = 0; e < 4; e++)
            tile[(r4 + e) * 33 + c] = W[(size_t)(ti * 32 + r4 + e) * 512 + tj * 32 + c];
    }
    __syncthreads();
    {
        int rr = t & 31, c4 = (t >> 5) * 4;
        #pragma unroll
        for (int e = 0; e < 4; e++)
            Wt[(size_t)mat * 262144 + (size_t)(tj * 32 + c4 + e) * 512 + ti * 32 + rr] =
                f2bf(tile[rr * 33 + c4 + e]);
    }
}

// ---------------- 64-row-tile bf16 MFMA GEMM, BK=64, XOR-swizzled LDS ----------
// Tile 64 x (NT*16). 4 waves; wave w owns rows [w*16, w*16+16). K = 512.
// LDS tile rows are 8 chunks of 16B; physical chunk = logical ^ (row&7), applied
// on the GLOBAL source side so global_load_lds's lane-contiguous dest works.
// Frag reads then hit 2-way banks (free) instead of 8/16-way.
__device__ inline void storeC(float* C, size_t i, float v) { C[i] = v; }
__device__ inline void storeC(unsigned short* C, size_t i, float v) { C[i] = f2bf(v); }

template <typename OUT, int NT>
__global__ __launch_bounds__(256) void gemm64(const unsigned short* __restrict__ A,
                                              const unsigned short* __restrict__ Bt,
                                              OUT* __restrict__ C, int Nstride) {
    __shared__ unsigned short As[64 * 64];
    __shared__ unsigned short Bs[NT * 16 * 64];
    const int t = threadIdx.x;
    const int w = t >> 6, l = t & 63;
    const int lm = l & 15;
    const int mBase = blockIdx.x * 64;
    const int nBase = blockIdx.y * (NT * 16);

    // staging slot s -> row s>>3, physical chunk s&7, logical chunk (s&7)^(row&7)
    const unsigned short* aptr[2];
    #pragma unroll
    for (int n = 0; n < 2; n++) {
        int s = t + n * 256;
        int r = s >> 3, lc = (s & 7) ^ (r & 7);
        aptr[n] = A + (size_t)(mBase + r) * 512 + lc * 8;
    }
    const unsigned short* bptr[NT / 2];
    #pragma unroll
    for (int n = 0; n < NT / 2; n++) {
        int s = t + n * 256;
        int r = s >> 3, lc = (s & 7) ^ (r & 7);
        bptr[n] = Bt + (size_t)(nBase + r) * 512 + lc * 8;
    }

    f32x4 acc[NT];
    #pragma unroll
    for (int j = 0; j < NT; j++) acc[j] = (f32x4){0.f, 0.f, 0.f, 0.f};

    for (int k0 = 0; k0 < 512; k0 += 64) {
        #pragma unroll
        for (int n = 0; n < 2; n++) async_load16(aptr[n] + k0, &As[(t + n * 256) * 8]);
        #pragma unroll
        for (int n = 0; n < NT / 2; n++) async_load16(bptr[n] + k0, &Bs[(t + n * 256) * 8]);
        __syncthreads();
        #pragma unroll
        for (int ks = 0; ks < 2; ks++) {
            const int koff = (((ks * 4 + (l >> 4)) ^ (lm & 7)) * 8);
            bf16x8 af = *(const bf16x8*)&As[(w * 16 + lm) * 64 + koff];
            #pragma unroll
            for (int j = 0; j < NT; j++) {
                bf16x8 bfr = *(const bf16x8*)&Bs[(j * 16 + lm) * 64 + koff];
                acc[j] = __builtin_amdgcn_mfma_f32_16x16x32_bf16(af, bfr, acc[j], 0, 0, 0);
            }
        }
        __syncthreads();
    }
    // C/D map: col = lane&15, row = (lane>>4)*4 + reg  [m89-verified]
    const int rRow = (l >> 4) * 4;
    #pragma unroll
    for (int j = 0; j < NT; j++)
        #pragma unroll
        for (int r = 0; r < 4; r++) {
            size_t row = (size_t)(mBase + w * 16 + rRow + r);
            size_t col = (size_t)(nBase + j * 16 + lm);
            storeC(C, row * (size_t)Nstride + col, acc[j][r]);
        }
}

// ---------------- MFMA sliding-window attention ----------------
// Block: 64 queries x 1 head x 1 batch; wave w -> queries [w*16, w*16+16).
// Keys j=0..191 <-> g = s0-127+j. Valid: j in [max(qi,127-s0), qi+127].
// K/Q staged async with the same XOR chunk swizzle (unpadded stride-64 rows).
__global__ __launch_bounds__(256) void attn_mfma(const unsigned short* __restrict__ QKV,
                                                 unsigned short* __restrict__ AO) {
    __shared__ unsigned short Ks[192 * 64];   // [key j][feat], chunk-swizzled
    __shared__ unsigned short Qs[64 * 64];    // [q][feat], chunk-swizzled
    __shared__ unsigned short Vs[64 * 200];   // [d][key j], chunk-swizzled
    __shared__ unsigned short Pb[4][16 * 40]; // per-wave P bounce

    const int t = threadIdx.x;
    const int w = t >> 6, l = t & 63;
    const int lm = l & 15;
    const int s0 = blockIdx.x * 64;
    const int h = blockIdx.y, b = blockIdx.z;
    const unsigned short* base = QKV + (size_t)b * SEQ * 1536;

    // async-stage K: 192 rows x 8 chunks = 1536 slots (6/thread)
    #pragma unroll
    for (int n = 0; n < 6; n++) {
        int i = t + n * 256;
        int j = i >> 3, c8 = i & 7;
        int lc = c8 ^ (j & 7);
        int g = s0 - 127 + j;
        g = g < 0 ? 0 : (g > SEQ - 1 ? SEQ - 1 : g);
        async_load16(base + (size_t)g * 1536 + 512 + h * 64 + lc * 8, &Ks[i * 8]);
    }
    // async-stage Q: 64 rows x 8 chunks = 512 slots (2/thread)
    #pragma unroll
    for (int n = 0; n < 2; n++) {
        int i = t + n * 256;
        int j = i >> 3, c8 = i & 7;
        int lc = c8 ^ (j & 7);
        async_load16(base + (size_t)(s0 + j) * 1536 + h * 64 + lc * 8, &Qs[i * 8]);
    }
    // stage V transposed: global row j (coalesced 16B) -> Vs[d][j] scalar writes.
    for (int i = t; i < 192 * 8; i += 256) {
        int j = i >> 3, c8 = i & 7;
        int g = s0 - 127 + j;
        g = g < 0 ? 0 : (g > SEQ - 1 ? SEQ - 1 : g);
        uint4 vv = *(const uint4*)(base + (size_t)g * 1536 + 1024 + h * 64 + c8 * 8);
        unsigned short e16[8];
        *(uint4*)e16 = vv;
        int chunk = (j >> 3) ^ c8;           // (d>>3)&7 == c8 for d in [8*c8, 8*c8+8)
        int off = chunk * 8 + (j & 7);
        #pragma unroll
        for (int e = 0; e < 8; e++)
            Vs[(c8 * 8 + e) * 200 + off] = e16[e];
    }
    __syncthreads();

    // ---- scores: S[16 q][192 j] via MFMA ----
    f32x4 sc[12];
    #pragma unroll
    for (int kb = 0; kb < 12; kb++) sc[kb] = (f32x4){0.f, 0.f, 0.f, 0.f};
    #pragma unroll
    for (int ks = 0; ks < 2; ks++) {
        const int cq = ks * 4 + (l >> 4);
        bf16x8 aq = *(const bf16x8*)&Qs[(w * 16 + lm) * 64 + ((cq ^ (lm & 7)) * 8)];
        #pragma unroll
        for (int kb = 0; kb < 12; kb++) {
            int row = kb * 16 + lm;
            bf16x8 bk = *(const bf16x8*)&Ks[row * 64 + ((cq ^ (row & 7)) * 8)];
            sc[kb] = __builtin_amdgcn_mfma_f32_16x16x32_bf16(aq, bk, sc[kb], 0, 0, 0);
        }
    }

    // ---- mask + scale + in-register softmax ----
    const int qr0 = (l >> 4) * 4;
    const int jlo_g = 127 - s0;
    float mrow[4] = {-1e30f, -1e30f, -1e30f, -1e30f};
    #pragma unroll
    for (int kb = 0; kb < 12; kb++) {
        int j = kb * 16 + lm;
        #pragma unroll
        for (int r = 0; r < 4; r++) {
            int qi = w * 16 + qr0 + r;
            bool valid = (j >= qi) & (j <= qi + 127) & (j >= jlo_g);
            float v = valid ? sc[kb][r] * 0.125f : -1e30f;
            sc[kb][r] = v;
            mrow[r] = fmaxf(mrow[r], v);
        }
    }
    #pragma unroll
    for (int r = 0; r < 4; r++) {
        mrow[r] = fmaxf(mrow[r], __shfl_xor(mrow[r], 1));
        mrow[r] = fmaxf(mrow[r], __shfl_xor(mrow[r], 2));
        mrow[r] = fmaxf(mrow[r], __shfl_xor(mrow[r], 4));
        mrow[r] = fmaxf(mrow[r], __shfl_xor(mrow[r], 8));
    }
    float srow[4] = {0.f, 0.f, 0.f, 0.f};
    #pragma unroll
    for (int kb = 0; kb < 12; kb++)
        #pragma unroll
        for (int r = 0; r < 4; r++) {
            float p = __expf(sc[kb][r] - mrow[r]);
            sc[kb][r] = p;
            srow[r] += p;
        }
    #pragma unroll
    for (int r = 0; r < 4; r++) {
        srow[r] += __shfl_xor(srow[r], 1);
        srow[r] += __shfl_xor(srow[r], 2);
        srow[r] += __shfl_xor(srow[r], 4);
        srow[r] += __shfl_xor(srow[r], 8);
        srow[r] = 1.f / srow[r];
    }

    // ---- PV: O[16 q][64 d]; P -> per-wave LDS bounce -> A-frag ----
    f32x4 ov[4];
    #pragma unroll
    for (int nb = 0; nb < 4; nb++) ov[nb] = (f32x4){0.f, 0.f, 0.f, 0.f};
    unsigned short* pb = &Pb[w][0];
    #pragma unroll
    for (int c = 0; c < 6; c++) {
        #pragma unroll
        for (int kk = 0; kk < 2; kk++)
            #pragma unroll
            for (int r = 0; r < 4; r++)
                pb[(qr0 + r) * 40 + kk * 16 + lm] = f2bf(sc[2 * c + kk][r]);
        bf16x8 ap = *(const bf16x8*)&pb[lm * 40 + (l >> 4) * 8];
        #pragma unroll
        for (int nb = 0; nb < 4; nb++) {
            int d = nb * 16 + lm;
            int cj = c * 4 + (l >> 4);                  // logical 16B chunk of j
            int off = ((cj ^ ((d >> 3) & 7)) * 8);
            bf16x8 bv = *(const bf16x8*)&Vs[d * 200 + off];
            ov[nb] = __builtin_amdgcn_mfma_f32_16x16x32_bf16(ap, bv, ov[nb], 0, 0, 0);
        }
    }

    // ---- epilogue ----
    #pragma unroll
    for (int nb = 0; nb < 4; nb++)
        #pragma unroll
        for (int r = 0; r < 4; r++) {
            size_t row = (size_t)(b * SEQ + s0 + w * 16 + qr0 + r);
            AO[row * 512 + h * 64 + nb * 16 + lm] = f2bf(ov[nb][r] * srow[r]);
        }
}

extern "C" void kernel_launch(void* const* d_in, const int* in_sizes, int n_in,
                              void* d_out, int out_size, void* d_ws, size_t ws_size,
                              hipStream_t stream) {
    const float* x  = (const float*)d_in[0];
    const float* Wq = (const float*)d_in[1];
    const float* Wk = (const float*)d_in[2];
    const float* Wv = (const float*)d_in[3];
    const float* Wo = (const float*)d_in[4];
    float* out = (float*)d_out;

    char* ws = (char*)d_ws;
    unsigned short* xc  = (unsigned short*)ws;                          // 4 MiB
    unsigned short* Wt  = (unsigned short*)(ws + 4u * 1024 * 1024);     // 2 MiB
    unsigned short* QKV = (unsigned short*)(ws + 6u * 1024 * 1024);     // 12 MiB
    unsigned short* AO  = (unsigned short*)(ws + 18u * 1024 * 1024);    // 4 MiB

    prep<<<3072, 256, 0, stream>>>(x, Wq, Wk, Wv, Wo, xc, Wt);
    // fused QKV projection: 64x128 tiles, BK=64 -> 768 blocks (3/CU)
    gemm64<unsigned short, 8><<<dim3(64, 12), 256, 0, stream>>>(xc, Wt, QKV, 1536);
    attn_mfma<<<dim3(32, 8, 2), 256, 0, stream>>>(QKV, AO);
    // output projection: 64x64 tiles, BK=64 -> 512 blocks (2/CU)
    gemm64<float, 4><<<dim3(64, 8), 256, 0, stream>>>(AO, Wt + 3 * 262144, out, 512);
}